// Round 1
// baseline (766.225 us; speedup 1.0000x reference)
//
#include <hip/hip_runtime.h>
#include <hip/hip_fp16.h>

typedef _Float16 half8 __attribute__((ext_vector_type(8)));
typedef float floatx4 __attribute__((ext_vector_type(4)));

#define KDIM 49152
#define NDIM 2048
#define MDIM 128
#define NKG 16
#define KSTEPS 96  // 96*32 = 3072 K per group; 16 groups * 3072 = 49152

// ---------------- K0: x (128,8,6144) f32 -> flat (128,49152) f16, flat[b, c*8+hh] = x[b,hh,c]
__global__ __launch_bounds__(256) void k0_relayout(const float* __restrict__ x, _Float16* __restrict__ A) {
  int c = blockIdx.x * 256 + threadIdx.x;   // 0..6143
  int b = blockIdx.y;                       // 0..127
  const float* xp = x + (size_t)b * KDIM + c;
  half8 v;
#pragma unroll
  for (int hh = 0; hh < 8; ++hh) v[hh] = (_Float16)xp[(size_t)hh * 6144];
  *(half8*)(A + (size_t)b * KDIM + (size_t)c * 8) = v;
}

// ---------------- K1: h-partials = flat(128x49152,f16) @ fc_w(49152x2048,f32->f16)
// grid (32 ntiles of 64 cols, 16 kgroups), 256 thr, no LDS, no barriers.
__global__ __launch_bounds__(256) void k1_gemm(const _Float16* __restrict__ A,
                                               const float* __restrict__ W,
                                               float* __restrict__ P) {
  const int nt   = blockIdx.x;       // 0..31
  const int kg   = blockIdx.y;       // 0..15
  const int tid  = threadIdx.x;
  const int wave = tid >> 6;
  const int lane = tid & 63;
  const int q    = lane >> 4;        // quad 0..3
  const int r    = lane & 15;
  const int mhalf  = wave >> 1;      // waves 0,1 -> rows 0..63 ; waves 2,3 -> rows 64..127
  const int cstrip = (wave & 1) << 5;
  const int colbase = nt * 64 + cstrip;

  const _Float16* aptr = A + (size_t)(mhalf * 64 + r) * KDIM + kg * (KSTEPS * 32) + q * 8;
  const float*    wptr = W + (size_t)(kg * (KSTEPS * 32) + q * 8) * NDIM + colbase + r;

  floatx4 acc[4][2];
#pragma unroll
  for (int mt = 0; mt < 4; ++mt)
#pragma unroll
    for (int ntl = 0; ntl < 2; ++ntl) acc[mt][ntl] = (floatx4){0.f, 0.f, 0.f, 0.f};

  half8 a_cur[4];
  float fb_cur[2][8];
#pragma unroll
  for (int mt = 0; mt < 4; ++mt) a_cur[mt] = *(const half8*)(aptr + (size_t)mt * 16 * KDIM);
#pragma unroll
  for (int ntl = 0; ntl < 2; ++ntl)
#pragma unroll
    for (int j = 0; j < 8; ++j) fb_cur[ntl][j] = wptr[(size_t)j * NDIM + ntl * 16];

  for (int ks = 0; ks < KSTEPS; ++ks) {
    half8 a_nxt[4];
    float fb_nxt[2][8];
    if (ks + 1 < KSTEPS) {
      const _Float16* ap = aptr + (ks + 1) * 32;
#pragma unroll
      for (int mt = 0; mt < 4; ++mt) a_nxt[mt] = *(const half8*)(ap + (size_t)mt * 16 * KDIM);
      const float* wp = wptr + (size_t)(ks + 1) * 32 * NDIM;
#pragma unroll
      for (int ntl = 0; ntl < 2; ++ntl)
#pragma unroll
        for (int j = 0; j < 8; ++j) fb_nxt[ntl][j] = wp[(size_t)j * NDIM + ntl * 16];
    }
    half8 bfr[2];
#pragma unroll
    for (int ntl = 0; ntl < 2; ++ntl)
#pragma unroll
      for (int j = 0; j < 8; ++j) bfr[ntl][j] = (_Float16)fb_cur[ntl][j];
#pragma unroll
    for (int mt = 0; mt < 4; ++mt)
#pragma unroll
      for (int ntl = 0; ntl < 2; ++ntl)
        acc[mt][ntl] = __builtin_amdgcn_mfma_f32_16x16x32_f16(a_cur[mt], bfr[ntl], acc[mt][ntl], 0, 0, 0);
#pragma unroll
    for (int mt = 0; mt < 4; ++mt) a_cur[mt] = a_nxt[mt];
#pragma unroll
    for (int ntl = 0; ntl < 2; ++ntl)
#pragma unroll
      for (int j = 0; j < 8; ++j) fb_cur[ntl][j] = fb_nxt[ntl][j];
  }

  float* pout = P + (size_t)kg * (MDIM * NDIM);
#pragma unroll
  for (int mt = 0; mt < 4; ++mt)
#pragma unroll
    for (int ntl = 0; ntl < 2; ++ntl)
#pragma unroll
      for (int rr = 0; rr < 4; ++rr) {
        int row = mhalf * 64 + mt * 16 + q * 4 + rr;   // C/D: col=lane&15, row=quad*4+reg
        int col = colbase + ntl * 16 + r;
        pout[(size_t)row * NDIM + col] = acc[mt][ntl][rr];
      }
}

// ---------------- K2: h = sum_kg P + fc_b
__global__ __launch_bounds__(256) void k2_reduce(const float* __restrict__ P,
                                                 const float* __restrict__ fc_b,
                                                 float* __restrict__ h) {
  int t = blockIdx.x * 256 + threadIdx.x;  // 0..262143
  float s = fc_b[t & (NDIM - 1)];
#pragma unroll
  for (int kg = 0; kg < NKG; ++kg) s += P[(size_t)kg * (MDIM * NDIM) + t];
  h[t] = s;
}

// ---------------- KW: W12 = li1_w(2048x1000) @ li2_w(1000x2); b12 = li1_b @ li2_w + li2_b
__global__ __launch_bounds__(256) void kw_fuse(const float* __restrict__ li1_w, const float* __restrict__ li1_b,
                                               const float* __restrict__ li2_w, const float* __restrict__ li2_b,
                                               float* __restrict__ W12, float* __restrict__ b12) {
  __shared__ float l2s[2000];
  __shared__ float red[256][2];
  int tid = threadIdx.x;
  for (int i = tid; i < 2000; i += 256) l2s[i] = li2_w[i];
  __syncthreads();
  if (blockIdx.x < 8) {
    int k = blockIdx.x * 256 + tid;
    const float* row = li1_w + (size_t)k * 1000;
    float a0 = 0.f, a1 = 0.f;
    for (int n = 0; n < 1000; n += 4) {
      float4 v = *(const float4*)(row + n);
      a0 += v.x * l2s[2 * n + 0] + v.y * l2s[2 * n + 2] + v.z * l2s[2 * n + 4] + v.w * l2s[2 * n + 6];
      a1 += v.x * l2s[2 * n + 1] + v.y * l2s[2 * n + 3] + v.z * l2s[2 * n + 5] + v.w * l2s[2 * n + 7];
    }
    W12[k * 2 + 0] = a0;
    W12[k * 2 + 1] = a1;
  } else {
    float p0 = 0.f, p1 = 0.f;
    for (int n = tid; n < 1000; n += 256) {
      float bb = li1_b[n];
      p0 += bb * l2s[2 * n + 0];
      p1 += bb * l2s[2 * n + 1];
    }
    red[tid][0] = p0; red[tid][1] = p1;
    __syncthreads();
    for (int s = 128; s > 0; s >>= 1) {
      if (tid < s) { red[tid][0] += red[tid + s][0]; red[tid][1] += red[tid + s][1]; }
      __syncthreads();
    }
    if (tid == 0) { b12[0] = red[0][0] + li2_b[0]; b12[1] = red[0][1] + li2_b[1]; }
  }
}

// ---------------- K3: everything after h, one block per batch, thread = position l
__global__ __launch_bounds__(256) void k3_tail(
    const float* __restrict__ h,
    const float* __restrict__ ln1_s, const float* __restrict__ ln1_b,
    const float* __restrict__ ln2_s, const float* __restrict__ ln2_b,
    const float* __restrict__ Wq, const float* __restrict__ Wk, const float* __restrict__ Wv,
    const float* __restrict__ Wg, const float* __restrict__ Wo,
    const float* __restrict__ gn_w, const float* __restrict__ gn_b,
    const float* __restrict__ fw1, const float* __restrict__ fb1,
    const float* __restrict__ fw2, const float* __restrict__ fb2,
    const float* __restrict__ W12, const float* __restrict__ b12,
    float* __restrict__ out) {
  const int b = blockIdx.x;
  const int l = threadIdx.x;
  __shared__ float KS[2][256][4];
  __shared__ float VS[2][256][8];
  __shared__ float rs[4][2];

  float X[8];
  const float* hp = h + (size_t)b * 2048 + l * 8;
#pragma unroll
  for (int i = 0; i < 8; ++i) X[i] = hp[i];

  // LN1
  float mean = 0.f;
#pragma unroll
  for (int i = 0; i < 8; ++i) mean += X[i];
  mean *= 0.125f;
  float var = 0.f;
#pragma unroll
  for (int i = 0; i < 8; ++i) { float d = X[i] - mean; var += d * d; }
  var *= 0.125f;
  float rstd = rsqrtf(var + 1e-5f);
  float Xn[8];
#pragma unroll
  for (int i = 0; i < 8; ++i) Xn[i] = (X[i] - mean) * rstd * ln1_s[i] + ln1_b[i];

  // xPos factors for position l (Dh=4: pairs use freq {1, 0.01}, scales sv^(l/512))
  float p = (float)l;
  float e = p * (1.0f / 512.0f);
  const float sv0 = 1.6f / 5.6f, sv1 = 3.6f / 5.6f;
  float s0 = exp2f(e * log2f(sv0));
  float s1 = exp2f(e * log2f(sv1));
  float c0 = cosf(p), n0 = sinf(p);
  float c1 = cosf(0.01f * p), n1 = sinf(0.01f * p);
  float is0 = 1.f / s0, is1 = 1.f / s1;

  float Qr[2][4];
#pragma unroll
  for (int hd = 0; hd < 2; ++hd) {
    float qv[4] = {0, 0, 0, 0}, kv[4] = {0, 0, 0, 0}, vv[8] = {0, 0, 0, 0, 0, 0, 0, 0};
#pragma unroll
    for (int c = 0; c < 8; ++c) {
      float xc = Xn[c];
#pragma unroll
      for (int d = 0; d < 4; ++d) {
        qv[d] += xc * Wq[hd * 32 + c * 4 + d];
        kv[d] += xc * Wk[hd * 32 + c * 4 + d];
      }
#pragma unroll
      for (int d = 0; d < 8; ++d) vv[d] += xc * Wv[hd * 64 + c * 8 + d];
    }
    Qr[hd][0] = (qv[0] * c0 - qv[1] * n0) * s0;
    Qr[hd][1] = (qv[1] * c0 + qv[0] * n0) * s0;
    Qr[hd][2] = (qv[2] * c1 - qv[3] * n1) * s1;
    Qr[hd][3] = (qv[3] * c1 + qv[2] * n1) * s1;
    KS[hd][l][0] = (kv[0] * c0 - kv[1] * n0) * is0;
    KS[hd][l][1] = (kv[1] * c0 + kv[0] * n0) * is0;
    KS[hd][l][2] = (kv[2] * c1 - kv[3] * n1) * is1;
    KS[hd][l][3] = (kv[3] * c1 + kv[2] * n1) * is1;
#pragma unroll
    for (int d = 0; d < 8; ++d) VS[hd][l][d] = vv[d];
  }
  __syncthreads();

  // retention: o_l = sum_{m<=l} gamma^(l-m) (Q_l.K_m) V_m   (ascending m -> LDS broadcast)
  float Yc[16];
#pragma unroll
  for (int hd = 0; hd < 2; ++hd) {
    float gam = (hd == 0) ? (1.f - 1.f / 32.f) : (1.f - 1.f / 512.f);
    float w = exp2f(p * log2f(gam));  // gamma^l
    float ig = 1.f / gam;
    float q0 = Qr[hd][0], q1 = Qr[hd][1], q2 = Qr[hd][2], q3 = Qr[hd][3];
    float o[8] = {0, 0, 0, 0, 0, 0, 0, 0};
    for (int m = 0; m <= l; ++m) {
      float s = (q0 * KS[hd][m][0] + q1 * KS[hd][m][1] + q2 * KS[hd][m][2] + q3 * KS[hd][m][3]) * w;
#pragma unroll
      for (int d = 0; d < 8; ++d) o[d] += s * VS[hd][m][d];
      w *= ig;
    }
    // groupnorm over this head's 8
    float gm = 0.f;
#pragma unroll
    for (int d = 0; d < 8; ++d) gm += o[d];
    gm *= 0.125f;
    float gv = 0.f;
#pragma unroll
    for (int d = 0; d < 8; ++d) { float dd = o[d] - gm; gv += dd * dd; }
    gv *= 0.125f;
    float grs = rsqrtf(gv + 1e-5f);
#pragma unroll
    for (int d = 0; d < 8; ++d) Yc[hd * 8 + d] = (o[d] - gm) * grs * gn_w[hd * 8 + d] + gn_b[hd * 8 + d];
  }

  // gate = swish(Xn@Wg); msr = (gate*gn)@Wo ; Y = msr + X
  float msr[8] = {0, 0, 0, 0, 0, 0, 0, 0};
#pragma unroll
  for (int j = 0; j < 16; ++j) {
    float g = 0.f;
#pragma unroll
    for (int c = 0; c < 8; ++c) g += Xn[c] * Wg[c * 16 + j];
    float gate = g / (1.f + expf(-g));
    float t = gate * Yc[j];
#pragma unroll
    for (int o2 = 0; o2 < 8; ++o2) msr[o2] += t * Wo[j * 8 + o2];
  }
  float Y[8];
#pragma unroll
  for (int i = 0; i < 8; ++i) Y[i] = msr[i] + X[i];

  // LN2
  float m2 = 0.f;
#pragma unroll
  for (int i = 0; i < 8; ++i) m2 += Y[i];
  m2 *= 0.125f;
  float v2 = 0.f;
#pragma unroll
  for (int i = 0; i < 8; ++i) { float d = Y[i] - m2; v2 += d * d; }
  v2 *= 0.125f;
  float rs2 = rsqrtf(v2 + 1e-5f);
  float Z[8];
#pragma unroll
  for (int i = 0; i < 8; ++i) Z[i] = (Y[i] - m2) * rs2 * ln2_s[i] + ln2_b[i];

  // FFN: gelu(Z@w1+b1)@w2+b2 ; X2 = ff + Y
  float ffh[8];
#pragma unroll
  for (int o2 = 0; o2 < 8; ++o2) {
    float t = fb1[o2];
#pragma unroll
    for (int c = 0; c < 8; ++c) t += Z[c] * fw1[c * 8 + o2];
    ffh[o2] = 0.5f * t * (1.f + erff(t * 0.70710678118654752f));
  }
  float X2[8];
#pragma unroll
  for (int o2 = 0; o2 < 8; ++o2) {
    float t = fb2[o2];
#pragma unroll
    for (int c = 0; c < 8; ++c) t += ffh[c] * fw2[c * 8 + o2];
    X2[o2] = t + Y[o2];
  }

  // fused head: out[b][j] = sum_k X2flat[k] * W12[k][j] + b12[j]
  float p0 = 0.f, p1 = 0.f;
  const float* wp = W12 + (size_t)l * 16;
#pragma unroll
  for (int i = 0; i < 8; ++i) { p0 += X2[i] * wp[2 * i]; p1 += X2[i] * wp[2 * i + 1]; }
#pragma unroll
  for (int off = 32; off > 0; off >>= 1) { p0 += __shfl_down(p0, off); p1 += __shfl_down(p1, off); }
  int wave = l >> 6, lane = l & 63;
  if (lane == 0) { rs[wave][0] = p0; rs[wave][1] = p1; }
  __syncthreads();
  if (l == 0) {
    out[b * 2 + 0] = rs[0][0] + rs[1][0] + rs[2][0] + rs[3][0] + b12[0];
    out[b * 2 + 1] = rs[0][1] + rs[1][1] + rs[2][1] + rs[3][1] + b12[1];
  }
}

extern "C" void kernel_launch(void* const* d_in, const int* in_sizes, int n_in,
                              void* d_out, int out_size, void* d_ws, size_t ws_size,
                              hipStream_t stream) {
  const float* x     = (const float*)d_in[0];
  const float* fc_w  = (const float*)d_in[1];
  const float* fc_b  = (const float*)d_in[2];
  const float* ln1_s = (const float*)d_in[3];
  const float* ln1_b = (const float*)d_in[4];
  const float* ln2_s = (const float*)d_in[5];
  const float* ln2_b = (const float*)d_in[6];
  const float* Wq    = (const float*)d_in[7];
  const float* Wk    = (const float*)d_in[8];
  const float* Wv    = (const float*)d_in[9];
  const float* Wg    = (const float*)d_in[10];
  const float* Wo    = (const float*)d_in[11];
  const float* gn_w  = (const float*)d_in[12];
  const float* gn_b  = (const float*)d_in[13];
  const float* fw1   = (const float*)d_in[14];
  const float* fb1   = (const float*)d_in[15];
  const float* fw2   = (const float*)d_in[16];
  const float* fb2   = (const float*)d_in[17];
  const float* li1_w = (const float*)d_in[18];
  const float* li1_b = (const float*)d_in[19];
  const float* li2_w = (const float*)d_in[20];
  const float* li2_b = (const float*)d_in[21];
  float* out = (float*)d_out;

  char* ws = (char*)d_ws;
  _Float16* A = (_Float16*)ws;                       // 12,582,912 B
  float* P    = (float*)(ws + 12582912);             // 16 * 1 MiB partials
  float* h    = (float*)(ws + 29360128);             // 1 MiB
  float* W12  = (float*)(ws + 30408704);             // 16 KiB
  float* b12  = (float*)(ws + 30425088);             // 8 B

  hipLaunchKernelGGL(k0_relayout, dim3(24, 128), dim3(256), 0, stream, x, A);
  hipLaunchKernelGGL(k1_gemm, dim3(32, 16), dim3(256), 0, stream, A, fc_w, P);
  hipLaunchKernelGGL(k2_reduce, dim3(1024), dim3(256), 0, stream, P, fc_b, h);
  hipLaunchKernelGGL(kw_fuse, dim3(9), dim3(256), 0, stream, li1_w, li1_b, li2_w, li2_b, W12, b12);
  hipLaunchKernelGGL(k3_tail, dim3(128), dim3(256), 0, stream, h,
                     ln1_s, ln1_b, ln2_s, ln2_b, Wq, Wk, Wv, Wg, Wo,
                     gn_w, gn_b, fw1, fb1, fw2, fb2, W12, b12, out);
}

// Round 2
// 730.390 us; speedup vs baseline: 1.0491x; 1.0491x over previous
//
#include <hip/hip_runtime.h>
#include <hip/hip_fp16.h>

typedef _Float16 half8 __attribute__((ext_vector_type(8)));
typedef float floatx4 __attribute__((ext_vector_type(4)));

#define KDIM 49152
#define NDIM 2048
#define MDIM 128
#define NKG 32
#define KSTEPS 48  // 48*32 = 1536 K per group; 32 groups * 1536 = 49152

// ---------------- K0: x (128,8,6144) f32 -> flat (128,49152) f16, flat[b, c*8+hh] = x[b,hh,c]
__global__ __launch_bounds__(256) void k0_relayout(const float* __restrict__ x, _Float16* __restrict__ A) {
  int c = blockIdx.x * 256 + threadIdx.x;   // 0..6143
  int b = blockIdx.y;                       // 0..127
  const float* xp = x + (size_t)b * KDIM + c;
  half8 v;
#pragma unroll
  for (int hh = 0; hh < 8; ++hh) v[hh] = (_Float16)xp[(size_t)hh * 6144];
  *(half8*)(A + (size_t)b * KDIM + (size_t)c * 8) = v;
}

// ---------------- K1: h-partials = flat(128x49152,f16) @ fc_w(49152x2048,f32->f16)
// grid (32 ntiles of 64 cols, 32 kgroups) = 1024 blocks (4/CU), 256 thr.
// No LDS, no barriers: register double-buffer with parity indexing (no copies,
// fine-grained vmcnt, ~2 K-steps of loads in flight per wave).
__global__ __launch_bounds__(256) void k1_gemm(const _Float16* __restrict__ A,
                                               const float* __restrict__ W,
                                               float* __restrict__ P) {
  const int nt   = blockIdx.x;       // 0..31
  const int kg   = blockIdx.y;       // 0..31
  const int tid  = threadIdx.x;
  const int wave = tid >> 6;
  const int lane = tid & 63;
  const int q    = lane >> 4;        // quad 0..3
  const int r    = lane & 15;
  const int mhalf  = wave >> 1;      // waves 0,1 -> rows 0..63 ; waves 2,3 -> rows 64..127
  const int colbase = nt * 64 + ((wave & 1) << 5);

  const _Float16* aptr = A + (size_t)(mhalf * 64 + r) * KDIM + kg * (KSTEPS * 32) + q * 8;
  const float*    wptr = W + (size_t)(kg * (KSTEPS * 32) + q * 8) * NDIM + colbase + r;

  floatx4 acc[4][2];
#pragma unroll
  for (int mt = 0; mt < 4; ++mt)
#pragma unroll
    for (int ntl = 0; ntl < 2; ++ntl) acc[mt][ntl] = (floatx4){0.f, 0.f, 0.f, 0.f};

  half8 ab[2][4];
  float wb[2][16];

#define LOADSTEP(buf, ks) do {                                                      \
    const _Float16* ap_ = aptr + (ks) * 32;                                         \
    _Pragma("unroll")                                                               \
    for (int mt = 0; mt < 4; ++mt) ab[buf][mt] = *(const half8*)(ap_ + (size_t)mt * 16 * KDIM); \
    const float* wp_ = wptr + (size_t)(ks) * 32 * NDIM;                             \
    _Pragma("unroll")                                                               \
    for (int ntl = 0; ntl < 2; ++ntl)                                               \
      _Pragma("unroll")                                                             \
      for (int j = 0; j < 8; ++j) wb[buf][ntl * 8 + j] = wp_[(size_t)j * NDIM + ntl * 16]; \
  } while (0)

#define COMPSTEP(buf) do {                                                          \
    half8 bf[2];                                                                    \
    _Pragma("unroll")                                                               \
    for (int ntl = 0; ntl < 2; ++ntl)                                               \
      _Pragma("unroll")                                                             \
      for (int j = 0; j < 8; ++j) bf[ntl][j] = (_Float16)wb[buf][ntl * 8 + j];      \
    _Pragma("unroll")                                                               \
    for (int mt = 0; mt < 4; ++mt)                                                  \
      _Pragma("unroll")                                                             \
      for (int ntl = 0; ntl < 2; ++ntl)                                             \
        acc[mt][ntl] = __builtin_amdgcn_mfma_f32_16x16x32_f16(ab[buf][mt], bf[ntl], acc[mt][ntl], 0, 0, 0); \
  } while (0)

  LOADSTEP(0, 0);
  LOADSTEP(1, 1);
  for (int ks = 0; ks < KSTEPS - 2; ks += 2) {
    COMPSTEP(0);
    LOADSTEP(0, ks + 2);
    COMPSTEP(1);
    LOADSTEP(1, ks + 3);
  }
  COMPSTEP(0);
  COMPSTEP(1);
#undef LOADSTEP
#undef COMPSTEP

  float* pout = P + (size_t)kg * (MDIM * NDIM);
#pragma unroll
  for (int mt = 0; mt < 4; ++mt)
#pragma unroll
    for (int ntl = 0; ntl < 2; ++ntl)
#pragma unroll
      for (int rr = 0; rr < 4; ++rr) {
        int row = mhalf * 64 + mt * 16 + q * 4 + rr;   // C/D: col=lane&15, row=quad*4+reg
        int col = colbase + ntl * 16 + r;
        pout[(size_t)row * NDIM + col] = acc[mt][ntl][rr];
      }
}

// ---------------- K2: h = sum_kg P + fc_b
__global__ __launch_bounds__(256) void k2_reduce(const float* __restrict__ P,
                                                 const float* __restrict__ fc_b,
                                                 float* __restrict__ h) {
  int t = blockIdx.x * 256 + threadIdx.x;  // 0..262143
  float s = fc_b[t & (NDIM - 1)];
#pragma unroll
  for (int kg = 0; kg < NKG; ++kg) s += P[(size_t)kg * (MDIM * NDIM) + t];
  h[t] = s;
}

// ---------------- KW: W12 = li1_w(2048x1000) @ li2_w(1000x2); b12 = li1_b @ li2_w + li2_b
// blocks 0..511: one wave per row of W12 (fully parallel stream of li1_w).
// block 512: bias reduction.
__global__ __launch_bounds__(256) void kw_fuse(const float* __restrict__ li1_w, const float* __restrict__ li1_b,
                                               const float* __restrict__ li2_w, const float* __restrict__ li2_b,
                                               float* __restrict__ W12, float* __restrict__ b12) {
  __shared__ float l2s[2000];
  int tid = threadIdx.x;
  for (int i = tid; i < 2000; i += 256) l2s[i] = li2_w[i];
  __syncthreads();
  if (blockIdx.x < 512) {
    int wave = tid >> 6, lane = tid & 63;
    int row = blockIdx.x * 4 + wave;
    const float* rp = li1_w + (size_t)row * 1000;   // 4000 B rows -> 16B aligned
    float a0 = 0.f, a1 = 0.f;
    for (int c = lane; c < 250; c += 64) {          // 250 float4 chunks per row
      float4 v  = *(const float4*)(rp + c * 4);
      float4 w0 = *(const float4*)(&l2s[8 * c]);
      float4 w1 = *(const float4*)(&l2s[8 * c + 4]);
      a0 += v.x * w0.x + v.y * w0.z + v.z * w1.x + v.w * w1.z;
      a1 += v.x * w0.y + v.y * w0.w + v.z * w1.y + v.w * w1.w;
    }
#pragma unroll
    for (int off = 32; off > 0; off >>= 1) { a0 += __shfl_down(a0, off); a1 += __shfl_down(a1, off); }
    if (lane == 0) { W12[row * 2 + 0] = a0; W12[row * 2 + 1] = a1; }
  } else {
    __shared__ float red[256][2];
    float p0 = 0.f, p1 = 0.f;
    for (int n = tid; n < 1000; n += 256) {
      float bb = li1_b[n];
      p0 += bb * l2s[2 * n + 0];
      p1 += bb * l2s[2 * n + 1];
    }
    red[tid][0] = p0; red[tid][1] = p1;
    __syncthreads();
    for (int s = 128; s > 0; s >>= 1) {
      if (tid < s) { red[tid][0] += red[tid + s][0]; red[tid][1] += red[tid + s][1]; }
      __syncthreads();
    }
    if (tid == 0) { b12[0] = red[0][0] + li2_b[0]; b12[1] = red[0][1] + li2_b[1]; }
  }
}

// ---------------- K3: everything after h, one block per batch, thread = position l
__global__ __launch_bounds__(256) void k3_tail(
    const float* __restrict__ h,
    const float* __restrict__ ln1_s, const float* __restrict__ ln1_b,
    const float* __restrict__ ln2_s, const float* __restrict__ ln2_b,
    const float* __restrict__ Wq, const float* __restrict__ Wk, const float* __restrict__ Wv,
    const float* __restrict__ Wg, const float* __restrict__ Wo,
    const float* __restrict__ gn_w, const float* __restrict__ gn_b,
    const float* __restrict__ fw1, const float* __restrict__ fb1,
    const float* __restrict__ fw2, const float* __restrict__ fb2,
    const float* __restrict__ W12, const float* __restrict__ b12,
    float* __restrict__ out) {
  const int b = blockIdx.x;
  const int l = threadIdx.x;
  __shared__ float KS[2][256][4];
  __shared__ float VS[2][256][8];
  __shared__ float rs[4][2];

  float X[8];
  const float* hp = h + (size_t)b * 2048 + l * 8;
#pragma unroll
  for (int i = 0; i < 8; ++i) X[i] = hp[i];

  // LN1
  float mean = 0.f;
#pragma unroll
  for (int i = 0; i < 8; ++i) mean += X[i];
  mean *= 0.125f;
  float var = 0.f;
#pragma unroll
  for (int i = 0; i < 8; ++i) { float d = X[i] - mean; var += d * d; }
  var *= 0.125f;
  float rstd = rsqrtf(var + 1e-5f);
  float Xn[8];
#pragma unroll
  for (int i = 0; i < 8; ++i) Xn[i] = (X[i] - mean) * rstd * ln1_s[i] + ln1_b[i];

  // xPos factors for position l (Dh=4: pair freqs {1, 0.01}, scales sv^(l/512))
  float p = (float)l;
  float e = p * (1.0f / 512.0f);
  const float sv0 = 1.6f / 5.6f, sv1 = 3.6f / 5.6f;
  float s0 = exp2f(e * log2f(sv0));
  float s1 = exp2f(e * log2f(sv1));
  float c0 = cosf(p), n0 = sinf(p);
  float c1 = cosf(0.01f * p), n1 = sinf(0.01f * p);
  float is0 = 1.f / s0, is1 = 1.f / s1;

  float Qr[2][4];
#pragma unroll
  for (int hd = 0; hd < 2; ++hd) {
    float qv[4] = {0, 0, 0, 0}, kv[4] = {0, 0, 0, 0}, vv[8] = {0, 0, 0, 0, 0, 0, 0, 0};
#pragma unroll
    for (int c = 0; c < 8; ++c) {
      float xc = Xn[c];
#pragma unroll
      for (int d = 0; d < 4; ++d) {
        qv[d] += xc * Wq[hd * 32 + c * 4 + d];
        kv[d] += xc * Wk[hd * 32 + c * 4 + d];
      }
#pragma unroll
      for (int d = 0; d < 8; ++d) vv[d] += xc * Wv[hd * 64 + c * 8 + d];
    }
    Qr[hd][0] = (qv[0] * c0 - qv[1] * n0) * s0;
    Qr[hd][1] = (qv[1] * c0 + qv[0] * n0) * s0;
    Qr[hd][2] = (qv[2] * c1 - qv[3] * n1) * s1;
    Qr[hd][3] = (qv[3] * c1 + qv[2] * n1) * s1;
    KS[hd][l][0] = (kv[0] * c0 - kv[1] * n0) * is0;
    KS[hd][l][1] = (kv[1] * c0 + kv[0] * n0) * is0;
    KS[hd][l][2] = (kv[2] * c1 - kv[3] * n1) * is1;
    KS[hd][l][3] = (kv[3] * c1 + kv[2] * n1) * is1;
#pragma unroll
    for (int d = 0; d < 8; ++d) VS[hd][l][d] = vv[d];
  }
  __syncthreads();

  // retention: o_l = sum_{m<=l} gamma^(l-m) (Q_l.K_m) V_m   (ascending m -> LDS broadcast)
  float Yc[16];
#pragma unroll
  for (int hd = 0; hd < 2; ++hd) {
    float gam = (hd == 0) ? (1.f - 1.f / 32.f) : (1.f - 1.f / 512.f);
    float w = exp2f(p * log2f(gam));  // gamma^l
    float ig = 1.f / gam;
    float q0 = Qr[hd][0], q1 = Qr[hd][1], q2 = Qr[hd][2], q3 = Qr[hd][3];
    float o[8] = {0, 0, 0, 0, 0, 0, 0, 0};
    for (int m = 0; m <= l; ++m) {
      float s = (q0 * KS[hd][m][0] + q1 * KS[hd][m][1] + q2 * KS[hd][m][2] + q3 * KS[hd][m][3]) * w;
#pragma unroll
      for (int d = 0; d < 8; ++d) o[d] += s * VS[hd][m][d];
      w *= ig;
    }
    // groupnorm over this head's 8
    float gm = 0.f;
#pragma unroll
    for (int d = 0; d < 8; ++d) gm += o[d];
    gm *= 0.125f;
    float gv = 0.f;
#pragma unroll
    for (int d = 0; d < 8; ++d) { float dd = o[d] - gm; gv += dd * dd; }
    gv *= 0.125f;
    float grs = rsqrtf(gv + 1e-5f);
#pragma unroll
    for (int d = 0; d < 8; ++d) Yc[hd * 8 + d] = (o[d] - gm) * grs * gn_w[hd * 8 + d] + gn_b[hd * 8 + d];
  }

  // gate = swish(Xn@Wg); msr = (gate*gn)@Wo ; Y = msr + X
  float msr[8] = {0, 0, 0, 0, 0, 0, 0, 0};
#pragma unroll
  for (int j = 0; j < 16; ++j) {
    float g = 0.f;
#pragma unroll
    for (int c = 0; c < 8; ++c) g += Xn[c] * Wg[c * 16 + j];
    float gate = g / (1.f + expf(-g));
    float t = gate * Yc[j];
#pragma unroll
    for (int o2 = 0; o2 < 8; ++o2) msr[o2] += t * Wo[j * 8 + o2];
  }
  float Y[8];
#pragma unroll
  for (int i = 0; i < 8; ++i) Y[i] = msr[i] + X[i];

  // LN2
  float m2 = 0.f;
#pragma unroll
  for (int i = 0; i < 8; ++i) m2 += Y[i];
  m2 *= 0.125f;
  float v2 = 0.f;
#pragma unroll
  for (int i = 0; i < 8; ++i) { float d = Y[i] - m2; v2 += d * d; }
  v2 *= 0.125f;
  float rs2 = rsqrtf(v2 + 1e-5f);
  float Z[8];
#pragma unroll
  for (int i = 0; i < 8; ++i) Z[i] = (Y[i] - m2) * rs2 * ln2_s[i] + ln2_b[i];

  // FFN: gelu(Z@w1+b1)@w2+b2 ; X2 = ff + Y
  float ffh[8];
#pragma unroll
  for (int o2 = 0; o2 < 8; ++o2) {
    float t = fb1[o2];
#pragma unroll
    for (int c = 0; c < 8; ++c) t += Z[c] * fw1[c * 8 + o2];
    ffh[o2] = 0.5f * t * (1.f + erff(t * 0.70710678118654752f));
  }
  float X2[8];
#pragma unroll
  for (int o2 = 0; o2 < 8; ++o2) {
    float t = fb2[o2];
#pragma unroll
    for (int c = 0; c < 8; ++c) t += ffh[c] * fw2[c * 8 + o2];
    X2[o2] = t + Y[o2];
  }

  // fused head: out[b][j] = sum_k X2flat[k] * W12[k][j] + b12[j]
  float p0 = 0.f, p1 = 0.f;
  const float* wp = W12 + (size_t)l * 16;
#pragma unroll
  for (int i = 0; i < 8; ++i) { p0 += X2[i] * wp[2 * i]; p1 += X2[i] * wp[2 * i + 1]; }
#pragma unroll
  for (int off = 32; off > 0; off >>= 1) { p0 += __shfl_down(p0, off); p1 += __shfl_down(p1, off); }
  int wave = l >> 6, lane = l & 63;
  if (lane == 0) { rs[wave][0] = p0; rs[wave][1] = p1; }
  __syncthreads();
  if (l == 0) {
    out[b * 2 + 0] = rs[0][0] + rs[1][0] + rs[2][0] + rs[3][0] + b12[0];
    out[b * 2 + 1] = rs[0][1] + rs[1][1] + rs[2][1] + rs[3][1] + b12[1];
  }
}

extern "C" void kernel_launch(void* const* d_in, const int* in_sizes, int n_in,
                              void* d_out, int out_size, void* d_ws, size_t ws_size,
                              hipStream_t stream) {
  const float* x     = (const float*)d_in[0];
  const float* fc_w  = (const float*)d_in[1];
  const float* fc_b  = (const float*)d_in[2];
  const float* ln1_s = (const float*)d_in[3];
  const float* ln1_b = (const float*)d_in[4];
  const float* ln2_s = (const float*)d_in[5];
  const float* ln2_b = (const float*)d_in[6];
  const float* Wq    = (const float*)d_in[7];
  const float* Wk    = (const float*)d_in[8];
  const float* Wv    = (const float*)d_in[9];
  const float* Wg    = (const float*)d_in[10];
  const float* Wo    = (const float*)d_in[11];
  const float* gn_w  = (const float*)d_in[12];
  const float* gn_b  = (const float*)d_in[13];
  const float* fw1   = (const float*)d_in[14];
  const float* fb1   = (const float*)d_in[15];
  const float* fw2   = (const float*)d_in[16];
  const float* fb2   = (const float*)d_in[17];
  const float* li1_w = (const float*)d_in[18];
  const float* li1_b = (const float*)d_in[19];
  const float* li2_w = (const float*)d_in[20];
  const float* li2_b = (const float*)d_in[21];
  float* out = (float*)d_out;

  char* ws = (char*)d_ws;
  _Float16* A = (_Float16*)ws;                       // 12,582,912 B
  float* P    = (float*)(ws + 12582912);             // 32 * 1 MiB partials
  float* h    = (float*)(ws + 46137344);             // 1 MiB
  float* W12  = (float*)(ws + 47185920);             // 16 KiB
  float* b12  = (float*)(ws + 47202304);             // 8 B

  hipLaunchKernelGGL(k0_relayout, dim3(24, 128), dim3(256), 0, stream, x, A);
  hipLaunchKernelGGL(k1_gemm, dim3(32, 32), dim3(256), 0, stream, A, fc_w, P);
  hipLaunchKernelGGL(k2_reduce, dim3(1024), dim3(256), 0, stream, P, fc_b, h);
  hipLaunchKernelGGL(kw_fuse, dim3(513), dim3(256), 0, stream, li1_w, li1_b, li2_w, li2_b, W12, b12);
  hipLaunchKernelGGL(k3_tail, dim3(128), dim3(256), 0, stream, h,
                     ln1_s, ln1_b, ln2_s, ln2_b, Wq, Wk, Wv, Wg, Wo,
                     gn_w, gn_b, fw1, fb1, fw2, fb2, W12, b12, out);
}